// Round 14
// baseline (153.606 us; speedup 1.0000x reference)
//
#include <hip/hip_runtime.h>

// DPQ embedding, MI355X. N=131072 tokens, EMB=128, D=8 subspaces x SUB=16, K=128 codes.
// Pipeline:
//  k1_stats:  gather x rows, stats. NEW: reg-staged double-buffered chunks
//             (global loads for c+1 issued before Gram of c; HBM latency hides
//             under the 1024cyc Gram burst), 2 syncthreads/chunk (was 3).
//  k2a/k2b:   deterministic two-stage tree-reduce of block partials (in-place)
//  k3_final:  stats + centroids -> alpha[k], beta[d][k]
//  k4_main:   T=4 ping-pong ds_read pipeline. FIX vs R13: sched_barrier(0)
//             after ISSUE as well -- R12/R13's leak was COMPUTE hoisting above
//             the volatile reads (LLVM moves C code across volatile asm), which
//             re-serialized read->wait->compute. Phase is now
//             ISSUE ; SB ; COMPUTE ; SB ; s_waitcnt ; SB.
// Pipe budget per k (T=4): DS/CU = 16w x 4 b128 x 12cyc = 768 (41us over 128k);
// VALU/SIMD = 4w x ~150cyc = 600 (34us). Overlapped target ~45us.
// History: R9 81.6 best; R10 scalar-K$ refuted; R11 s_load-in-loop drains DS;
// R12 96 (T=8 + spill, VGPR 108<128 needed); R13 91 (fence hole).

constexpr int NTOK = 131072;   // 1024*128
constexpr int ST   = 2320;     // stats stride (2312 used, padded)
constexpr float EPS = 0.001f;

typedef float v2f __attribute__((ext_vector_type(2)));

__device__ inline float rlane(float v, int lane) {
    return __int_as_float(__builtin_amdgcn_readlane(__float_as_int(v), lane));
}

// stats layout: G: d*256 + s*16 + s'  (2048)
//               Sx: 2048 + d*16 + s   (128)
//               h : 2176 + d*16 + s   (128)
//               S2: 2304 + d          (8)    -> 2312 total

__global__ __launch_bounds__(256) void k1_stats(const int* __restrict__ ids,
                                                const float* __restrict__ wemb,
                                                float* __restrict__ partials,
                                                int tpb)
{
    __shared__ float xs[2][32][132];  // double-buffered 32 tokens x 128 (pad 132)
    __shared__ float nrm[32][8];
    const int t = threadIdx.x;
    const int b = blockIdx.x;

    float g[4][4];
#pragma unroll
    for (int i = 0; i < 4; ++i)
#pragma unroll
        for (int j = 0; j < 4; ++j) g[i][j] = 0.f;
    float sx = 0.f, hh = 0.f, s2 = 0.f;

    const int d_g = t >> 4;                 // t<128: Gram task (d, 4x4 tile)
    const int r0  = ((t >> 2) & 3) << 2;
    const int c0  = (t & 3) << 2;
    const int u   = t & 127;                // t>=128: (d,s) task
    const int d_s = u >> 4;
    const int s_s = u & 15;
    // load roles: rep 0..3 -> i = t + rep*256, token n = i>>5, float4 slot f = i&31
    const int ln[4] = { (t + 0) >> 5, (t + 256) >> 5, (t + 512) >> 5, (t + 768) >> 5 };
    const int lf[4] = { (t + 0) & 31, (t + 256) & 31, (t + 512) & 31, (t + 768) & 31 };

    const int nchunks = tpb >> 5;
    float4 v[4];

    // prologue: load + write chunk 0
    {
        const int n0 = b * tpb;
#pragma unroll
        for (int rep = 0; rep < 4; ++rep)
            v[rep] = *(const float4*)(wemb + (size_t)ids[n0 + ln[rep]] * 128 + lf[rep] * 4);
#pragma unroll
        for (int rep = 0; rep < 4; ++rep)
            *(float4*)(&xs[0][ln[rep]][lf[rep] * 4]) = v[rep];
    }

    for (int ch = 0; ch < nchunks; ++ch) {
        const int cur = ch & 1;
        __syncthreads();                       // xs[cur] visible; prev h done
        // ---- issue next chunk's global loads (latency hides under Gram) ----
        if (ch + 1 < nchunks) {
            const int n0 = b * tpb + (ch + 1) * 32;
#pragma unroll
            for (int rep = 0; rep < 4; ++rep)
                v[rep] = *(const float4*)(wemb + (size_t)ids[n0 + ln[rep]] * 128 + lf[rep] * 4);
        }
        // ---- phase 1: Gram (t<128) | norms + Sx (t>=128) ----
        if (t < 128) {
            for (int n = 0; n < 32; ++n) {
                const float* xp = &xs[cur][n][d_g * 16];
                float4 av = *(const float4*)(xp + r0);
                float4 bv = *(const float4*)(xp + c0);
                float aa[4] = {av.x, av.y, av.z, av.w};
                float bb[4] = {bv.x, bv.y, bv.z, bv.w};
#pragma unroll
                for (int i = 0; i < 4; ++i)
#pragma unroll
                    for (int j = 0; j < 4; ++j)
                        g[i][j] = fmaf(aa[i], bb[j], g[i][j]);
            }
        } else {
            // 256 norms / 128 threads = 2 each
#pragma unroll
            for (int rep = 0; rep < 2; ++rep) {
                const int tau = u + rep * 128;
                const int n = tau >> 3, dd = tau & 7;
                const float* xp = &xs[cur][n][dd * 16];
                float acc = 0.f;
#pragma unroll
                for (int q = 0; q < 16; ++q) acc = fmaf(xp[q], xp[q], acc);
                nrm[n][dd] = acc;
            }
            for (int n = 0; n < 32; ++n) sx += xs[cur][n][d_s * 16 + s_s];
        }
        // ---- write staged chunk into the other buffer ----
        if (ch + 1 < nchunks) {
#pragma unroll
            for (int rep = 0; rep < 4; ++rep)
                *(float4*)(&xs[cur ^ 1][ln[rep]][lf[rep] * 4]) = v[rep];
        }
        __syncthreads();                       // nrm ready; xs[cur^1] written
        // ---- phase 2: h, S2 (t>=128); xs[cur] still intact ----
        if (t >= 128) {
            for (int n = 0; n < 32; ++n) {
                float nv = nrm[n][d_s];
                hh = fmaf(nv, xs[cur][n][d_s * 16 + s_s], hh);
                if (s_s == 0) s2 = fmaf(nv, nv, s2);
            }
        }
    }

    float* pb = partials + (size_t)b * ST;
    if (t < 128) {
        const int base = d_g * 256;
#pragma unroll
        for (int i = 0; i < 4; ++i)
#pragma unroll
            for (int j = 0; j < 4; ++j)
                pb[base + (r0 + i) * 16 + (c0 + j)] = g[i][j];
    } else {
        pb[2048 + d_s * 16 + s_s] = sx;
        pb[2176 + d_s * 16 + s_s] = hh;
        if (s_s == 0) pb[2304 + d_s] = s2;
    }
}

// ---- stage A: fold nb blocks down to 32, in place. grid (10, 32). ----
__global__ __launch_bounds__(256) void k2a_reduce(float* __restrict__ partials, int nb)
{
    const int idx = blockIdx.x * 256 + threadIdx.x;
    if (idx >= 2312) return;
    const int y = blockIdx.y;          // 0..31
    float acc[8] = {0.f, 0.f, 0.f, 0.f, 0.f, 0.f, 0.f, 0.f};
    int b = y;
    while (b + 7 * 32 < nb) {
#pragma unroll
        for (int u = 0; u < 8; ++u)
            acc[u] += partials[(size_t)(b + u * 32) * ST + idx];
        b += 8 * 32;
    }
    while (b < nb) { acc[0] += partials[(size_t)b * ST + idx]; b += 32; }
    float s = ((acc[0] + acc[1]) + (acc[2] + acc[3]))
            + ((acc[4] + acc[5]) + (acc[6] + acc[7]));
    partials[(size_t)y * ST + idx] = s;
}

// ---- stage B: sum the 32 survivors (L2-resident, fully unrolled). grid 10. ----
__global__ __launch_bounds__(256) void k2b_reduce(const float* __restrict__ partials,
                                                  float* __restrict__ stats)
{
    const int idx = blockIdx.x * 256 + threadIdx.x;
    if (idx >= 2312) return;
    float acc[8] = {0.f, 0.f, 0.f, 0.f, 0.f, 0.f, 0.f, 0.f};
#pragma unroll
    for (int j = 0; j < 4; ++j)
#pragma unroll
        for (int u = 0; u < 8; ++u)
            acc[u] += partials[(size_t)(j * 8 + u) * ST + idx];
    stats[idx] = ((acc[0] + acc[1]) + (acc[2] + acc[3]))
               + ((acc[4] + acc[5]) + (acc[6] + acc[7]));
}

__global__ __launch_bounds__(128) void k3_final(const float* __restrict__ stats,
                                                const float* __restrict__ centroids,
                                                float2* __restrict__ ab)
{
    __shared__ float st[2312];
    const int t = threadIdx.x;
    for (int i = t; i < 2312; i += 128) st[i] = stats[i];
    __syncthreads();
    const int k = t;   // 128 threads, one per code

    double Sn[8], Sn_tot = 0.0, S2_tot = 0.0;
#pragma unroll
    for (int d = 0; d < 8; ++d) {
        double s = 0.0;
        for (int ss = 0; ss < 16; ++ss) s += (double)st[d * 256 + ss * 17];
        Sn[d] = s; Sn_tot += s;
        S2_tot += (double)st[2304 + d];
    }
    double sr = -Sn_tot, sr2 = S2_tot;
    double ncd[8];
    for (int d = 0; d < 8; ++d) {
        const float* cp = centroids + d * 2048 + k * 16;
        float cv[16];
#pragma unroll
        for (int s = 0; s < 16; ++s) cv[s] = cp[s];
        double nc = 0, cdSx = 0, ch = 0, cGc = 0;
        for (int s = 0; s < 16; ++s) {
            nc   += (double)cv[s] * cv[s];
            cdSx += (double)cv[s] * st[2048 + d * 16 + s];
            ch   += (double)cv[s] * st[2176 + d * 16 + s];
            double rd = 0;
            for (int s2i = 0; s2i < 16; ++s2i)
                rd += (double)st[d * 256 + s * 16 + s2i] * cv[s2i];
            cGc += (double)cv[s] * rd;
        }
        ncd[d] = nc;
        sr  += 2.0 * cdSx - (double)NTOK * nc;
        sr2 += 4.0 * cGc + (double)NTOK * nc * nc + 2.0 * nc * Sn[d]
               - 4.0 * ch - 4.0 * nc * cdSx;
    }
    const double M = (double)NTOK * 8.0;
    double mean = sr / M;
    double var  = sr2 / M - mean * mean;
    float alpha = (float)(1.0 / sqrt(var + (double)EPS));
#pragma unroll
    for (int d = 0; d < 8; ++d) {
        float beta = (float)((double)alpha * (-ncd[d] - mean));
        ab[d * 128 + k] = make_float2(2.f * alpha, beta);
    }
}

// 4 tokens/thread, one d per blockIdx.y, 256-thread blocks, launch_bounds(256,4)
// (cap 128 VGPR; live ~112). Ping-pong, 2 k per iteration, fully fenced:
//   ISSUE(B,k+1); SB; COMPUTE(A,k); SB; waitcnt; SB;
//   ISSUE(A,k+2); SB; COMPUTE(B,k+1); SB; waitcnt; SB;
// gb via per-lane preload + readlane (VALU pipe; zero SMEM/extra-DS in loop).
__global__ __launch_bounds__(256, 4) void k4_main(const int* __restrict__ ids,
                                                  const float* __restrict__ wemb,
                                                  const float* __restrict__ centroids,
                                                  const float2* __restrict__ ab,
                                                  float* __restrict__ out)
{
    __shared__ __align__(16) float cs[128 * 16];   // 8KB centroids for this d

    const int t = threadIdx.x;        // 0..255
    const int d = blockIdx.y;
    const float* cd = centroids + (size_t)d * 2048;

    // stage centroids: 512 float4 -> 2 per thread
#pragma unroll
    for (int i = 0; i < 2; ++i)
        ((float4*)cs)[t + i * 256] = ((const float4*)cd)[t + i * 256];

    // per-lane gb: lane l holds (2a,b) for k=l and k=64+l
    const int lane = t & 63;
    const float2 g_lo = ab[(size_t)d * 128 + lane];
    const float2 g_hi = ab[(size_t)d * 128 + 64 + lane];

    const int nbase = blockIdx.x * 1024 + t;   // 4 tokens, stride 256
    v2f x[4][8];
    v2f nxv[4];
    float best[4];
    int   code[4];
#pragma unroll
    for (int j = 0; j < 4; ++j) {
        const int n = nbase + j * 256;
        const float* xp = wemb + (size_t)ids[n] * 128 + d * 16;
        float s = 0.f;
#pragma unroll
        for (int q = 0; q < 4; ++q) {
            float4 v = *(const float4*)(xp + q * 4);
            x[j][q * 2]     = (v2f){v.x, v.y};
            x[j][q * 2 + 1] = (v2f){v.z, v.w};
            s += v.x * v.x + v.y * v.y + v.z * v.z + v.w * v.w;
        }
        nxv[j] = (v2f){-0.5f * s, 0.f}; // score = 2a*(dot - nx/2) + beta
        best[j] = -3.4e38f;
        code[j] = 0;
    }

    __syncthreads();

    const unsigned cs_base = (unsigned)(unsigned long long)(const void*)&cs[0];

    // prologue: k=0 row into set A (plain reads; compiler inserts its wait)
    float4 A0 = *(const float4*)(&cs[0]);
    float4 A1 = *(const float4*)(&cs[4]);
    float4 A2 = *(const float4*)(&cs[8]);
    float4 A3 = *(const float4*)(&cs[12]);
    float4 B0, B1, B2, B3;

#define COMPUTE(R0, R1, R2, R3, KK)                                          \
    {                                                                        \
        const int kk_ = (KK);                                                \
        const int kl_ = kk_ & 63;                                            \
        const float ga_ = rlane(kk_ < 64 ? g_lo.x : g_hi.x, kl_);            \
        const float gb_ = rlane(kk_ < 64 ? g_lo.y : g_hi.y, kl_);            \
        const v2f cc0 = (v2f){R0.x, R0.y}, cc1 = (v2f){R0.z, R0.w};          \
        const v2f cc2 = (v2f){R1.x, R1.y}, cc3 = (v2f){R1.z, R1.w};          \
        const v2f cc4 = (v2f){R2.x, R2.y}, cc5 = (v2f){R2.z, R2.w};          \
        const v2f cc6 = (v2f){R3.x, R3.y}, cc7 = (v2f){R3.z, R3.w};          \
        _Pragma("unroll")                                                    \
        for (int j = 0; j < 4; ++j) {                                        \
            v2f a = __builtin_elementwise_fma(cc0, x[j][0], nxv[j]);         \
            a = __builtin_elementwise_fma(cc1, x[j][1], a);                  \
            a = __builtin_elementwise_fma(cc2, x[j][2], a);                  \
            a = __builtin_elementwise_fma(cc3, x[j][3], a);                  \
            a = __builtin_elementwise_fma(cc4, x[j][4], a);                  \
            a = __builtin_elementwise_fma(cc5, x[j][5], a);                  \
            a = __builtin_elementwise_fma(cc6, x[j][6], a);                  \
            a = __builtin_elementwise_fma(cc7, x[j][7], a);                  \
            float acc = a[0] + a[1];                                         \
            float sc = fmaf(ga_, acc, gb_);                                  \
            bool p = sc > best[j];   /* strict > keeps FIRST max */          \
            best[j] = p ? sc : best[j];                                      \
            code[j] = p ? kk_ : code[j];                                     \
        }                                                                    \
    }

#define ISSUE(R0, R1, R2, R3, KK)                                            \
    {                                                                        \
        const unsigned ra_ = cs_base + (unsigned)(((KK) & 127) * 64);        \
        asm volatile("ds_read_b128 %0, %1"           : "=v"(R0) : "v"(ra_)); \
        asm volatile("ds_read_b128 %0, %1 offset:16" : "=v"(R1) : "v"(ra_)); \
        asm volatile("ds_read_b128 %0, %1 offset:32" : "=v"(R2) : "v"(ra_)); \
        asm volatile("ds_read_b128 %0, %1 offset:48" : "=v"(R3) : "v"(ra_)); \
    }                                                                        \
    __builtin_amdgcn_sched_barrier(0);   /* reads stay ABOVE compute */

#define DRAIN()                                                              \
    __builtin_amdgcn_sched_barrier(0);   /* compute stays ABOVE wait  */     \
    asm volatile("s_waitcnt lgkmcnt(0)");                                    \
    __builtin_amdgcn_sched_barrier(0);   /* consumers stay BELOW wait */

#pragma unroll 1
    for (int k = 0; k < 128; k += 2) {
        ISSUE(B0, B1, B2, B3, k + 1)       // prefetch odd row
        COMPUTE(A0, A1, A2, A3, k)         // compute even row under the reads
        DRAIN()
        ISSUE(A0, A1, A2, A3, k + 2)       // prefetch next even row (wraps once)
        COMPUTE(B0, B1, B2, B3, k + 1)     // compute odd row
        DRAIN()
    }
#undef COMPUTE
#undef ISSUE
#undef DRAIN

#pragma unroll
    for (int j = 0; j < 4; ++j) {
        const int n = nbase + j * 256;
        const float* cw = cd + code[j] * 16;   // global, L1-hot 8KB set
        float* op = out + (size_t)n * 128 + d * 16;
#pragma unroll
        for (int q = 0; q < 4; ++q) {
            float4 cv = *(const float4*)(cw + q * 4);
            float x0 = x[j][q * 2][0],     x1 = x[j][q * 2][1];
            float x2 = x[j][q * 2 + 1][0], x3 = x[j][q * 2 + 1][1];
            float4 o;
            // match reference: out = x + (c - x) in fp32 (not just c)
            o.x = x0 + (cv.x - x0);
            o.y = x1 + (cv.y - x1);
            o.z = x2 + (cv.z - x2);
            o.w = x3 + (cv.w - x3);
            *(float4*)(op + q * 4) = o;
        }
    }
}

extern "C" void kernel_launch(void* const* d_in, const int* in_sizes, int n_in,
                              void* d_out, int out_size, void* d_ws, size_t ws_size,
                              hipStream_t stream)
{
    const int* ids    = (const int*)d_in[0];
    const float* wemb = (const float*)d_in[1];
    const float* cent = (const float*)d_in[2];
    float* out = (float*)d_out;
    float* ws  = (float*)d_ws;

    // choose pass-1 block count by available workspace
    int p1b = 1024;
    if (ws_size < ((size_t)1024 * ST + 2320 + 2048) * 4) p1b = 512;
    if (ws_size < ((size_t)512  * ST + 2320 + 2048) * 4) p1b = 256;
    if (ws_size < ((size_t)256  * ST + 2320 + 2048) * 4) p1b = 128;
    const int tpb = NTOK / p1b;

    float* partials = ws;
    float* stats    = ws + (size_t)p1b * ST;
    float2* ab      = (float2*)(stats + 2320);

    hipLaunchKernelGGL(k1_stats,   dim3(p1b),     dim3(256), 0, stream, ids, wemb, partials, tpb);
    hipLaunchKernelGGL(k2a_reduce, dim3(10, 32),  dim3(256), 0, stream, partials, p1b);
    hipLaunchKernelGGL(k2b_reduce, dim3(10),      dim3(256), 0, stream, partials, stats);
    hipLaunchKernelGGL(k3_final,   dim3(1),       dim3(128), 0, stream, stats, cent, ab);
    hipLaunchKernelGGL(k4_main,    dim3(128, 8),  dim3(256), 0, stream, ids, wemb, cent, ab, out);
}

// Round 15
// 147.293 us; speedup vs baseline: 1.0429x; 1.0429x over previous
//
#include <hip/hip_runtime.h>

// DPQ embedding, MI355X. N=131072 tokens, EMB=128, D=8 subspaces x SUB=16, K=128 codes.
// Pipeline:
//  k1_stats:  gather x rows, accumulate per-block moment stats (R13 version; the
//             R14 reg-staged dbuf regressed and was reverted)
//  k2a/k2b:   deterministic two-stage tree-reduce of block partials (in-place)
//  k3_final:  stats + centroids -> alpha[k], beta[d][k]
//  k4_main:   T=4, pk_fma. Centroid stream moved OFF the DS pipe: wave-uniform
//             address laundered through empty asm into a VGPR -> compiler must
//             emit global_load_dwordx4 (VMEM, L1-broadcast, vmcnt-pipelined)
//             instead of s_load (R10's serial SMEM convoy) or ds_read (R9's
//             DS-pipe saturation). Only gbs (1KB) stays in LDS.
// Decisive model (R9 post-mortem): R9's 81.6us == DS 42.7 + VALU 35.8 SUMMED.
// 16 waves x 5 DS/k = 800cyc/CU/k backlog cannot be hidden by depth-1 prefetch
// (168cyc compute) -- 5 asm-scheduling rounds (R11-R14) all confirmed. VMEM/k
// = 64 merged L1 reqs ~256cyc << VALU 672 -> VALU-bound by construction.
// History: R9 81.6 best; R10 110 (SMEM); R12-R14 91-107 (asm fence attempts).

constexpr int NTOK = 131072;   // 1024*128
constexpr int ST   = 2320;     // stats stride (2312 used, padded)
constexpr float EPS = 0.001f;

typedef float v2f __attribute__((ext_vector_type(2)));

// stats layout: G: d*256 + s*16 + s'  (2048)
//               Sx: 2048 + d*16 + s   (128)
//               h : 2176 + d*16 + s   (128)
//               S2: 2304 + d          (8)    -> 2312 total

__global__ __launch_bounds__(256) void k1_stats(const int* __restrict__ ids,
                                                const float* __restrict__ wemb,
                                                float* __restrict__ partials,
                                                int tpb)
{
    __shared__ float xs[32][132];   // 32 tokens x 128 floats, padded to 132
    __shared__ float nrm[32][8];
    const int t = threadIdx.x;
    const int b = blockIdx.x;

    float g[4][4];
#pragma unroll
    for (int i = 0; i < 4; ++i)
#pragma unroll
        for (int j = 0; j < 4; ++j) g[i][j] = 0.f;
    float sx = 0.f, hh = 0.f, s2 = 0.f;

    const int d_g = t >> 4;                 // t<128: Gram task (d, 4x4 tile)
    const int r0  = ((t >> 2) & 3) << 2;
    const int c0  = (t & 3) << 2;
    const int u   = t & 127;                // t>=128: (d,s) task
    const int d_s = u >> 4;
    const int s_s = u & 15;

    const int nchunks = tpb >> 5;
    for (int ch = 0; ch < nchunks; ++ch) {
        const int n0 = b * tpb + ch * 32;
        // ---- load 32 token rows (coalesced: 32 lanes x float4 = one 512B row) ----
#pragma unroll
        for (int rep = 0; rep < 4; ++rep) {
            int i = t + rep * 256;
            int n = i >> 5, f = i & 31;
            int id = ids[n0 + n];
            float4 v = *(const float4*)(wemb + (size_t)id * 128 + f * 4);
            *(float4*)(&xs[n][f * 4]) = v;
        }
        __syncthreads();
        // ---- per-(n,d) norms: 256 threads = 32x8 ----
        {
            int n = t >> 3, dd = t & 7;
            const float* xp = &xs[n][dd * 16];
            float4 a = *(const float4*)(xp);
            float4 bq = *(const float4*)(xp + 4);
            float4 c = *(const float4*)(xp + 8);
            float4 dq = *(const float4*)(xp + 12);
            float acc = a.x*a.x + a.y*a.y + a.z*a.z + a.w*a.w;
            acc += bq.x*bq.x + bq.y*bq.y + bq.z*bq.z + bq.w*bq.w;
            acc += c.x*c.x + c.y*c.y + c.z*c.z + c.w*c.w;
            acc += dq.x*dq.x + dq.y*dq.y + dq.z*dq.z + dq.w*dq.w;
            nrm[n][dd] = acc;
        }
        __syncthreads();
        // ---- accumulate stats over the chunk ----
        if (t < 128) {
            for (int n = 0; n < 32; ++n) {
                const float* xp = &xs[n][d_g * 16];
                float4 av = *(const float4*)(xp + r0);
                float4 bv = *(const float4*)(xp + c0);
                float aa[4] = {av.x, av.y, av.z, av.w};
                float bb[4] = {bv.x, bv.y, bv.z, bv.w};
#pragma unroll
                for (int i = 0; i < 4; ++i)
#pragma unroll
                    for (int j = 0; j < 4; ++j)
                        g[i][j] = fmaf(aa[i], bb[j], g[i][j]);
            }
        } else {
            for (int n = 0; n < 32; ++n) {
                float xv = xs[n][d_s * 16 + s_s];
                float nv = nrm[n][d_s];
                sx += xv;
                hh = fmaf(nv, xv, hh);
                if (s_s == 0) s2 = fmaf(nv, nv, s2);
            }
        }
        __syncthreads();
    }
    float* pb = partials + (size_t)b * ST;
    if (t < 128) {
        const int base = d_g * 256;
#pragma unroll
        for (int i = 0; i < 4; ++i)
#pragma unroll
            for (int j = 0; j < 4; ++j)
                pb[base + (r0 + i) * 16 + (c0 + j)] = g[i][j];
    } else {
        pb[2048 + d_s * 16 + s_s] = sx;
        pb[2176 + d_s * 16 + s_s] = hh;
        if (s_s == 0) pb[2304 + d_s] = s2;
    }
}

// ---- stage A: fold nb blocks down to 32, in place. grid (10, 32). ----
__global__ __launch_bounds__(256) void k2a_reduce(float* __restrict__ partials, int nb)
{
    const int idx = blockIdx.x * 256 + threadIdx.x;
    if (idx >= 2312) return;
    const int y = blockIdx.y;          // 0..31
    float acc[8] = {0.f, 0.f, 0.f, 0.f, 0.f, 0.f, 0.f, 0.f};
    int b = y;
    while (b + 7 * 32 < nb) {
#pragma unroll
        for (int u = 0; u < 8; ++u)
            acc[u] += partials[(size_t)(b + u * 32) * ST + idx];
        b += 8 * 32;
    }
    while (b < nb) { acc[0] += partials[(size_t)b * ST + idx]; b += 32; }
    float s = ((acc[0] + acc[1]) + (acc[2] + acc[3]))
            + ((acc[4] + acc[5]) + (acc[6] + acc[7]));
    partials[(size_t)y * ST + idx] = s;
}

// ---- stage B: sum the 32 survivors (L2-resident, fully unrolled). grid 10. ----
__global__ __launch_bounds__(256) void k2b_reduce(const float* __restrict__ partials,
                                                  float* __restrict__ stats)
{
    const int idx = blockIdx.x * 256 + threadIdx.x;
    if (idx >= 2312) return;
    float acc[8] = {0.f, 0.f, 0.f, 0.f, 0.f, 0.f, 0.f, 0.f};
#pragma unroll
    for (int j = 0; j < 4; ++j)
#pragma unroll
        for (int u = 0; u < 8; ++u)
            acc[u] += partials[(size_t)(j * 8 + u) * ST + idx];
    stats[idx] = ((acc[0] + acc[1]) + (acc[2] + acc[3]))
               + ((acc[4] + acc[5]) + (acc[6] + acc[7]));
}

__global__ __launch_bounds__(128) void k3_final(const float* __restrict__ stats,
                                                const float* __restrict__ centroids,
                                                float2* __restrict__ ab)
{
    __shared__ float st[2312];
    const int t = threadIdx.x;
    for (int i = t; i < 2312; i += 128) st[i] = stats[i];
    __syncthreads();
    const int k = t;   // 128 threads, one per code

    double Sn[8], Sn_tot = 0.0, S2_tot = 0.0;
#pragma unroll
    for (int d = 0; d < 8; ++d) {
        double s = 0.0;
        for (int ss = 0; ss < 16; ++ss) s += (double)st[d * 256 + ss * 17];
        Sn[d] = s; Sn_tot += s;
        S2_tot += (double)st[2304 + d];
    }
    double sr = -Sn_tot, sr2 = S2_tot;
    double ncd[8];
    for (int d = 0; d < 8; ++d) {
        const float* cp = centroids + d * 2048 + k * 16;
        float cv[16];
#pragma unroll
        for (int s = 0; s < 16; ++s) cv[s] = cp[s];
        double nc = 0, cdSx = 0, ch = 0, cGc = 0;
        for (int s = 0; s < 16; ++s) {
            nc   += (double)cv[s] * cv[s];
            cdSx += (double)cv[s] * st[2048 + d * 16 + s];
            ch   += (double)cv[s] * st[2176 + d * 16 + s];
            double rd = 0;
            for (int s2i = 0; s2i < 16; ++s2i)
                rd += (double)st[d * 256 + s * 16 + s2i] * cv[s2i];
            cGc += (double)cv[s] * rd;
        }
        ncd[d] = nc;
        sr  += 2.0 * cdSx - (double)NTOK * nc;
        sr2 += 4.0 * cGc + (double)NTOK * nc * nc + 2.0 * nc * Sn[d]
               - 4.0 * ch - 4.0 * nc * cdSx;
    }
    const double M = (double)NTOK * 8.0;
    double mean = sr / M;
    double var  = sr2 / M - mean * mean;
    float alpha = (float)(1.0 / sqrt(var + (double)EPS));
#pragma unroll
    for (int d = 0; d < 8; ++d) {
        float beta = (float)((double)alpha * (-ncd[d] - mean));
        ab[d * 128 + k] = make_float2(2.f * alpha, beta);
    }
}

// 4 tokens/thread, one d per blockIdx.y, 256-thread blocks, launch_bounds(256,4).
// Centroids read from GLOBAL via a VGPR-laundered pointer: all 64 lanes issue
// the same address -> TA merges to one L1 transaction, broadcast. The k-loop
// uses the VMEM pipe (compiler pipelines vmcnt natively across unroll-2); DS
// pipe carries only gbs (1 b64/k). VALU-bound by ~2.6x margin.
__global__ __launch_bounds__(256, 4) void k4_main(const int* __restrict__ ids,
                                                  const float* __restrict__ wemb,
                                                  const float* __restrict__ centroids,
                                                  const float2* __restrict__ ab,
                                                  float* __restrict__ out)
{
    __shared__ float2 gbs[128];       // 1KB: (2*alpha, beta)

    const int t = threadIdx.x;        // 0..255
    const int d = blockIdx.y;
    const float* cd = centroids + (size_t)d * 2048;

    // Launder the centroid base pointer through an empty asm: the compiler can
    // no longer prove wave-uniformity, so k-loop loads stay on the VECTOR
    // memory path (global_load_dwordx4 + vmcnt) instead of folding to s_load.
    const float* cdv = cd;
    asm("" : "+v"(cdv));

    if (t < 128) gbs[t] = ab[(size_t)d * 128 + t];

    const int nbase = blockIdx.x * 1024 + t;   // 4 tokens, stride 256
    v2f x[4][8];
    v2f nxv[4];
    float best[4];
    int   code[4];
#pragma unroll
    for (int j = 0; j < 4; ++j) {
        const int n = nbase + j * 256;
        const float* xp = wemb + (size_t)ids[n] * 128 + d * 16;
        float s = 0.f;
#pragma unroll
        for (int q = 0; q < 4; ++q) {
            float4 v = *(const float4*)(xp + q * 4);
            x[j][q * 2]     = (v2f){v.x, v.y};
            x[j][q * 2 + 1] = (v2f){v.z, v.w};
            s += v.x * v.x + v.y * v.y + v.z * v.z + v.w * v.w;
        }
        nxv[j] = (v2f){-0.5f * s, 0.f}; // score = 2a*(dot - nx/2) + beta
        best[j] = -3.4e38f;
        code[j] = 0;
    }

    __syncthreads();

#pragma unroll 2
    for (int k = 0; k < 128; ++k) {
        // uniform-address global loads -> one merged L1 request each, broadcast
        const float4 c0 = *(const float4*)(cdv + k * 16 + 0);
        const float4 c1 = *(const float4*)(cdv + k * 16 + 4);
        const float4 c2 = *(const float4*)(cdv + k * 16 + 8);
        const float4 c3 = *(const float4*)(cdv + k * 16 + 12);
        const float2 g  = gbs[k];          // lone DS op, pipe idle otherwise
        const v2f cc0 = (v2f){c0.x, c0.y}, cc1 = (v2f){c0.z, c0.w};
        const v2f cc2 = (v2f){c1.x, c1.y}, cc3 = (v2f){c1.z, c1.w};
        const v2f cc4 = (v2f){c2.x, c2.y}, cc5 = (v2f){c2.z, c2.w};
        const v2f cc6 = (v2f){c3.x, c3.y}, cc7 = (v2f){c3.z, c3.w};
#pragma unroll
        for (int j = 0; j < 4; ++j) {
            v2f a = __builtin_elementwise_fma(cc0, x[j][0], nxv[j]);
            a = __builtin_elementwise_fma(cc1, x[j][1], a);
            a = __builtin_elementwise_fma(cc2, x[j][2], a);
            a = __builtin_elementwise_fma(cc3, x[j][3], a);
            a = __builtin_elementwise_fma(cc4, x[j][4], a);
            a = __builtin_elementwise_fma(cc5, x[j][5], a);
            a = __builtin_elementwise_fma(cc6, x[j][6], a);
            a = __builtin_elementwise_fma(cc7, x[j][7], a);
            float acc = a[0] + a[1];
            float sc = fmaf(g.x, acc, g.y);
            bool p = sc > best[j];         // strict > keeps FIRST max (argmax tie rule)
            best[j] = p ? sc : best[j];
            code[j] = p ? k : code[j];
        }
    }

#pragma unroll
    for (int j = 0; j < 4; ++j) {
        const int n = nbase + j * 256;
        const float* cw = cd + code[j] * 16;   // divergent, L1-hot 8KB set
        float* op = out + (size_t)n * 128 + d * 16;
#pragma unroll
        for (int q = 0; q < 4; ++q) {
            float4 cv = *(const float4*)(cw + q * 4);
            float x0 = x[j][q * 2][0],     x1 = x[j][q * 2][1];
            float x2 = x[j][q * 2 + 1][0], x3 = x[j][q * 2 + 1][1];
            float4 o;
            // match reference: out = x + (c - x) in fp32 (not just c)
            o.x = x0 + (cv.x - x0);
            o.y = x1 + (cv.y - x1);
            o.z = x2 + (cv.z - x2);
            o.w = x3 + (cv.w - x3);
            *(float4*)(op + q * 4) = o;
        }
    }
}

extern "C" void kernel_launch(void* const* d_in, const int* in_sizes, int n_in,
                              void* d_out, int out_size, void* d_ws, size_t ws_size,
                              hipStream_t stream)
{
    const int* ids    = (const int*)d_in[0];
    const float* wemb = (const float*)d_in[1];
    const float* cent = (const float*)d_in[2];
    float* out = (float*)d_out;
    float* ws  = (float*)d_ws;

    // choose pass-1 block count by available workspace
    int p1b = 1024;
    if (ws_size < ((size_t)1024 * ST + 2320 + 2048) * 4) p1b = 512;
    if (ws_size < ((size_t)512  * ST + 2320 + 2048) * 4) p1b = 256;
    if (ws_size < ((size_t)256  * ST + 2320 + 2048) * 4) p1b = 128;
    const int tpb = NTOK / p1b;

    float* partials = ws;
    float* stats    = ws + (size_t)p1b * ST;
    float2* ab      = (float2*)(stats + 2320);

    hipLaunchKernelGGL(k1_stats,   dim3(p1b),     dim3(256), 0, stream, ids, wemb, partials, tpb);
    hipLaunchKernelGGL(k2a_reduce, dim3(10, 32),  dim3(256), 0, stream, partials, p1b);
    hipLaunchKernelGGL(k2b_reduce, dim3(10),      dim3(256), 0, stream, partials, stats);
    hipLaunchKernelGGL(k3_final,   dim3(1),       dim3(128), 0, stream, stats, cent, ab);
    hipLaunchKernelGGL(k4_main,    dim3(128, 8),  dim3(256), 0, stream, ids, wemb, cent, ab, out);
}

// Round 16
// 144.708 us; speedup vs baseline: 1.0615x; 1.0179x over previous
//
#include <hip/hip_runtime.h>

// DPQ embedding, MI355X. N=131072 tokens, EMB=128, D=8 subspaces x SUB=16, K=128 codes.
// Pipeline:
//  k1_stats:  gather x rows, accumulate per-block moment stats (proven R13 version)
//  k2a/k2b:   deterministic two-stage tree-reduce of block partials (in-place)
//  k3_final:  stats + centroids -> alpha[k], beta[d][k]
//  k4_main:   REGISTER-RESIDENT centroids. Lane l holds row l (16 VGPR); per k
//             the row is broadcast via v_readlane (VALU->SGPR) and consumed as
//             the SGPR operand of v_fma. The k-loop contains ZERO memory ops --
//             no DS, no SMEM, no VMEM. Two half-loops (rows 0-63 then reload
//             64-127) keep reg-set indexing compile-time (rule #20).
// Why: every memory pipe was measured and lost. R9 (LDS broadcast) 81.6us =
// DS 42.7 + VALU 35.8 SUMMED (queue backlog >> prefetch cover); SMEM (R10) and
// VMEM-broadcast (R15) both 110us; asm schedules (R11-R14) 85-107us. Single-
// pipe VALU floor: 99 inst/k/wave x 2cyc x 4 waves x 128k = 42us.
// History: R9 81.6 best / R10 110 / R11 85.5 / R12 96 / R13 91 / R14 107 / R15 110.

constexpr int NTOK = 131072;   // 1024*128
constexpr int ST   = 2320;     // stats stride (2312 used, padded)
constexpr float EPS = 0.001f;

__device__ inline float rlane(float v, int lane) {
    return __int_as_float(__builtin_amdgcn_readlane(__float_as_int(v), lane));
}

// stats layout: G: d*256 + s*16 + s'  (2048)
//               Sx: 2048 + d*16 + s   (128)
//               h : 2176 + d*16 + s   (128)
//               S2: 2304 + d          (8)    -> 2312 total

__global__ __launch_bounds__(256) void k1_stats(const int* __restrict__ ids,
                                                const float* __restrict__ wemb,
                                                float* __restrict__ partials,
                                                int tpb)
{
    __shared__ float xs[32][132];   // 32 tokens x 128 floats, padded to 132
    __shared__ float nrm[32][8];
    const int t = threadIdx.x;
    const int b = blockIdx.x;

    float g[4][4];
#pragma unroll
    for (int i = 0; i < 4; ++i)
#pragma unroll
        for (int j = 0; j < 4; ++j) g[i][j] = 0.f;
    float sx = 0.f, hh = 0.f, s2 = 0.f;

    const int d_g = t >> 4;                 // t<128: Gram task (d, 4x4 tile)
    const int r0  = ((t >> 2) & 3) << 2;
    const int c0  = (t & 3) << 2;
    const int u   = t & 127;                // t>=128: (d,s) task
    const int d_s = u >> 4;
    const int s_s = u & 15;

    const int nchunks = tpb >> 5;
    for (int ch = 0; ch < nchunks; ++ch) {
        const int n0 = b * tpb + ch * 32;
        // ---- load 32 token rows (coalesced: 32 lanes x float4 = one 512B row) ----
#pragma unroll
        for (int rep = 0; rep < 4; ++rep) {
            int i = t + rep * 256;
            int n = i >> 5, f = i & 31;
            int id = ids[n0 + n];
            float4 v = *(const float4*)(wemb + (size_t)id * 128 + f * 4);
            *(float4*)(&xs[n][f * 4]) = v;
        }
        __syncthreads();
        // ---- per-(n,d) norms: 256 threads = 32x8 ----
        {
            int n = t >> 3, dd = t & 7;
            const float* xp = &xs[n][dd * 16];
            float4 a = *(const float4*)(xp);
            float4 bq = *(const float4*)(xp + 4);
            float4 c = *(const float4*)(xp + 8);
            float4 dq = *(const float4*)(xp + 12);
            float acc = a.x*a.x + a.y*a.y + a.z*a.z + a.w*a.w;
            acc += bq.x*bq.x + bq.y*bq.y + bq.z*bq.z + bq.w*bq.w;
            acc += c.x*c.x + c.y*c.y + c.z*c.z + c.w*c.w;
            acc += dq.x*dq.x + dq.y*dq.y + dq.z*dq.z + dq.w*dq.w;
            nrm[n][dd] = acc;
        }
        __syncthreads();
        // ---- accumulate stats over the chunk ----
        if (t < 128) {
            for (int n = 0; n < 32; ++n) {
                const float* xp = &xs[n][d_g * 16];
                float4 av = *(const float4*)(xp + r0);
                float4 bv = *(const float4*)(xp + c0);
                float aa[4] = {av.x, av.y, av.z, av.w};
                float bb[4] = {bv.x, bv.y, bv.z, bv.w};
#pragma unroll
                for (int i = 0; i < 4; ++i)
#pragma unroll
                    for (int j = 0; j < 4; ++j)
                        g[i][j] = fmaf(aa[i], bb[j], g[i][j]);
            }
        } else {
            for (int n = 0; n < 32; ++n) {
                float xv = xs[n][d_s * 16 + s_s];
                float nv = nrm[n][d_s];
                sx += xv;
                hh = fmaf(nv, xv, hh);
                if (s_s == 0) s2 = fmaf(nv, nv, s2);
            }
        }
        __syncthreads();
    }
    float* pb = partials + (size_t)b * ST;
    if (t < 128) {
        const int base = d_g * 256;
#pragma unroll
        for (int i = 0; i < 4; ++i)
#pragma unroll
            for (int j = 0; j < 4; ++j)
                pb[base + (r0 + i) * 16 + (c0 + j)] = g[i][j];
    } else {
        pb[2048 + d_s * 16 + s_s] = sx;
        pb[2176 + d_s * 16 + s_s] = hh;
        if (s_s == 0) pb[2304 + d_s] = s2;
    }
}

// ---- stage A: fold nb blocks down to 32, in place. grid (10, 32). ----
__global__ __launch_bounds__(256) void k2a_reduce(float* __restrict__ partials, int nb)
{
    const int idx = blockIdx.x * 256 + threadIdx.x;
    if (idx >= 2312) return;
    const int y = blockIdx.y;          // 0..31
    float acc[8] = {0.f, 0.f, 0.f, 0.f, 0.f, 0.f, 0.f, 0.f};
    int b = y;
    while (b + 7 * 32 < nb) {
#pragma unroll
        for (int u = 0; u < 8; ++u)
            acc[u] += partials[(size_t)(b + u * 32) * ST + idx];
        b += 8 * 32;
    }
    while (b < nb) { acc[0] += partials[(size_t)b * ST + idx]; b += 32; }
    float s = ((acc[0] + acc[1]) + (acc[2] + acc[3]))
            + ((acc[4] + acc[5]) + (acc[6] + acc[7]));
    partials[(size_t)y * ST + idx] = s;
}

// ---- stage B: sum the 32 survivors (L2-resident, fully unrolled). grid 10. ----
__global__ __launch_bounds__(256) void k2b_reduce(const float* __restrict__ partials,
                                                  float* __restrict__ stats)
{
    const int idx = blockIdx.x * 256 + threadIdx.x;
    if (idx >= 2312) return;
    float acc[8] = {0.f, 0.f, 0.f, 0.f, 0.f, 0.f, 0.f, 0.f};
#pragma unroll
    for (int j = 0; j < 4; ++j)
#pragma unroll
        for (int u = 0; u < 8; ++u)
            acc[u] += partials[(size_t)(j * 8 + u) * ST + idx];
    stats[idx] = ((acc[0] + acc[1]) + (acc[2] + acc[3]))
               + ((acc[4] + acc[5]) + (acc[6] + acc[7]));
}

__global__ __launch_bounds__(128) void k3_final(const float* __restrict__ stats,
                                                const float* __restrict__ centroids,
                                                float2* __restrict__ ab)
{
    __shared__ float st[2312];
    const int t = threadIdx.x;
    for (int i = t; i < 2312; i += 128) st[i] = stats[i];
    __syncthreads();
    const int k = t;   // 128 threads, one per code

    double Sn[8], Sn_tot = 0.0, S2_tot = 0.0;
#pragma unroll
    for (int d = 0; d < 8; ++d) {
        double s = 0.0;
        for (int ss = 0; ss < 16; ++ss) s += (double)st[d * 256 + ss * 17];
        Sn[d] = s; Sn_tot += s;
        S2_tot += (double)st[2304 + d];
    }
    double sr = -Sn_tot, sr2 = S2_tot;
    double ncd[8];
    for (int d = 0; d < 8; ++d) {
        const float* cp = centroids + d * 2048 + k * 16;
        float cv[16];
#pragma unroll
        for (int s = 0; s < 16; ++s) cv[s] = cp[s];
        double nc = 0, cdSx = 0, ch = 0, cGc = 0;
        for (int s = 0; s < 16; ++s) {
            nc   += (double)cv[s] * cv[s];
            cdSx += (double)cv[s] * st[2048 + d * 16 + s];
            ch   += (double)cv[s] * st[2176 + d * 16 + s];
            double rd = 0;
            for (int s2i = 0; s2i < 16; ++s2i)
                rd += (double)st[d * 256 + s * 16 + s2i] * cv[s2i];
            cGc += (double)cv[s] * rd;
        }
        ncd[d] = nc;
        sr  += 2.0 * cdSx - (double)NTOK * nc;
        sr2 += 4.0 * cGc + (double)NTOK * nc * nc + 2.0 * nc * Sn[d]
               - 4.0 * ch - 4.0 * nc * cdSx;
    }
    const double M = (double)NTOK * 8.0;
    double mean = sr / M;
    double var  = sr2 / M - mean * mean;
    float alpha = (float)(1.0 / sqrt(var + (double)EPS));
#pragma unroll
    for (int d = 0; d < 8; ++d) {
        float beta = (float)((double)alpha * (-ncd[d] - mean));
        ab[d * 128 + k] = make_float2(2.f * alpha, beta);
    }
}

// 4 tokens/thread, one d per blockIdx.y, 256-thread blocks, launch_bounds(256,4).
// Wave-register-resident centroids: lane l holds row (half*64+l) in cr[16].
// Per k: v_readlane broadcasts the row (and its (2a,b)) to SGPRs; v_fma_f32
// consumes the SGPR operand directly. k-loop = pure VALU, zero memory ops.
// Two half-loops; cr reloaded between halves (keeps indexing compile-time).
__global__ __launch_bounds__(256, 4) void k4_main(const int* __restrict__ ids,
                                                  const float* __restrict__ wemb,
                                                  const float* __restrict__ centroids,
                                                  const float2* __restrict__ ab,
                                                  float* __restrict__ out)
{
    const int t = threadIdx.x;        // 0..255
    const int d = blockIdx.y;
    const int lane = t & 63;
    const float* cd = centroids + (size_t)d * 2048;

    const int nbase = blockIdx.x * 1024 + t;   // 4 tokens, stride 256
    float x[4][16];
    float nx[4], best[4];
    int   code[4];
#pragma unroll
    for (int j = 0; j < 4; ++j) {
        const int n = nbase + j * 256;
        const float* xp = wemb + (size_t)ids[n] * 128 + d * 16;
        float s = 0.f;
#pragma unroll
        for (int q = 0; q < 4; ++q) {
            float4 v = *(const float4*)(xp + q * 4);
            x[j][q * 4 + 0] = v.x; x[j][q * 4 + 1] = v.y;
            x[j][q * 4 + 2] = v.z; x[j][q * 4 + 3] = v.w;
            s += v.x * v.x + v.y * v.y + v.z * v.z + v.w * v.w;
        }
        nx[j] = -0.5f * s;             // score = 2a*(dot - nx/2) + beta
        best[j] = -3.4e38f;
        code[j] = 0;
    }

    // half 0: lane l holds row l (coalesced: wave reads 4KB contiguous)
    float cr[16];
#pragma unroll
    for (int q = 0; q < 4; ++q) {
        float4 v = *(const float4*)(cd + lane * 16 + q * 4);
        cr[q * 4 + 0] = v.x; cr[q * 4 + 1] = v.y;
        cr[q * 4 + 2] = v.z; cr[q * 4 + 3] = v.w;
    }
    float2 gcur = ab[(size_t)d * 128 + lane];

#define KHALF(KOFF)                                                          \
    _Pragma("unroll 4")                                                      \
    for (int k = 0; k < 64; ++k) {                                           \
        const float ga_ = rlane(gcur.x, k);                                  \
        const float gb_ = rlane(gcur.y, k);                                  \
        float ck[16];                                                        \
        _Pragma("unroll")                                                    \
        for (int i = 0; i < 16; ++i) ck[i] = rlane(cr[i], k);                \
        _Pragma("unroll")                                                    \
        for (int j = 0; j < 4; ++j) {                                        \
            float acc = nx[j];                                               \
            _Pragma("unroll")                                                \
            for (int i = 0; i < 16; ++i) acc = fmaf(ck[i], x[j][i], acc);    \
            float sc = fmaf(ga_, acc, gb_);                                  \
            bool p = sc > best[j];   /* strict > keeps FIRST max */          \
            best[j] = p ? sc : best[j];                                      \
            code[j] = p ? (k + KOFF) : code[j];                              \
        }                                                                    \
    }

    KHALF(0)

    // half 1: reload lane rows 64+l and their (2a,b)
#pragma unroll
    for (int q = 0; q < 4; ++q) {
        float4 v = *(const float4*)(cd + (64 + lane) * 16 + q * 4);
        cr[q * 4 + 0] = v.x; cr[q * 4 + 1] = v.y;
        cr[q * 4 + 2] = v.z; cr[q * 4 + 3] = v.w;
    }
    gcur = ab[(size_t)d * 128 + 64 + lane];

    KHALF(64)
#undef KHALF

#pragma unroll
    for (int j = 0; j < 4; ++j) {
        const int n = nbase + j * 256;
        const float* cw = cd + code[j] * 16;   // divergent, L1-hot 8KB set
        float* op = out + (size_t)n * 128 + d * 16;
#pragma unroll
        for (int q = 0; q < 4; ++q) {
            float4 cv = *(const float4*)(cw + q * 4);
            float4 o;
            // match reference: out = x + (c - x) in fp32 (not just c)
            o.x = x[j][q * 4 + 0] + (cv.x - x[j][q * 4 + 0]);
            o.y = x[j][q * 4 + 1] + (cv.y - x[j][q * 4 + 1]);
            o.z = x[j][q * 4 + 2] + (cv.z - x[j][q * 4 + 2]);
            o.w = x[j][q * 4 + 3] + (cv.w - x[j][q * 4 + 3]);
            *(float4*)(op + q * 4) = o;
        }
    }
}

extern "C" void kernel_launch(void* const* d_in, const int* in_sizes, int n_in,
                              void* d_out, int out_size, void* d_ws, size_t ws_size,
                              hipStream_t stream)
{
    const int* ids    = (const int*)d_in[0];
    const float* wemb = (const float*)d_in[1];
    const float* cent = (const float*)d_in[2];
    float* out = (float*)d_out;
    float* ws  = (float*)d_ws;

    // choose pass-1 block count by available workspace
    int p1b = 1024;
    if (ws_size < ((size_t)1024 * ST + 2320 + 2048) * 4) p1b = 512;
    if (ws_size < ((size_t)512  * ST + 2320 + 2048) * 4) p1b = 256;
    if (ws_size < ((size_t)256  * ST + 2320 + 2048) * 4) p1b = 128;
    const int tpb = NTOK / p1b;

    float* partials = ws;
    float* stats    = ws + (size_t)p1b * ST;
    float2* ab      = (float2*)(stats + 2320);

    hipLaunchKernelGGL(k1_stats,   dim3(p1b),     dim3(256), 0, stream, ids, wemb, partials, tpb);
    hipLaunchKernelGGL(k2a_reduce, dim3(10, 32),  dim3(256), 0, stream, partials, p1b);
    hipLaunchKernelGGL(k2b_reduce, dim3(10),      dim3(256), 0, stream, partials, stats);
    hipLaunchKernelGGL(k3_final,   dim3(1),       dim3(128), 0, stream, stats, cent, ab);
    hipLaunchKernelGGL(k4_main,    dim3(128, 8),  dim3(256), 0, stream, ids, wemb, cent, ab, out);
}

// Round 17
// 127.461 us; speedup vs baseline: 1.2051x; 1.1353x over previous
//
#include <hip/hip_runtime.h>

// DPQ embedding, MI355X. N=131072 tokens, EMB=128, D=8 subspaces x SUB=16, K=128 codes.
// Pipeline:
//  k1_stats:  gather x rows, accumulate per-block moment stats. p1b raised to
//             2048 (8 blocks/CU, 16 waves) to hide the cold-gather latency.
//  k2a/k2b:   deterministic two-stage tree-reduce of block partials (in-place)
//  k3_final:  stats + centroids -> alpha[k], beta[d][k]
//  k4_main:   R9 (proven 81.6us) with exactly two deltas:
//             (1) gbs removed from LDS -> per-lane (2a,b) preload + v_readlane
//                 in two half-loops (4 DS ops/k instead of 5; -20% DS time).
//             (2) winner-read from global L1 (R9's LDS epilogue had 1.19M
//                 bank conflicts).
// Scoreboard (16 rounds): LDS-broadcast 81.6 beats SMEM 110 / VMEM 110 /
// reg+readlane 114 (spilled) / all asm schedules 85-107. Model: k4 = DS-pipe
// 16w x 5rd x 12cyc = 960cyc/CU/k (51us) + VALU 36us, poorly overlapped.
// DS/token-d = 10/T invariant; T<=4 forced by 4 waves/SIMD. This round: DS
// 960->768 cyc/CU/k via the only removable read.

constexpr int NTOK = 131072;   // 1024*128
constexpr int ST   = 2320;     // stats stride (2312 used, padded)
constexpr float EPS = 0.001f;

typedef float v2f __attribute__((ext_vector_type(2)));

__device__ inline float rlane(float v, int lane) {
    return __int_as_float(__builtin_amdgcn_readlane(__float_as_int(v), lane));
}

// stats layout: G: d*256 + s*16 + s'  (2048)
//               Sx: 2048 + d*16 + s   (128)
//               h : 2176 + d*16 + s   (128)
//               S2: 2304 + d          (8)    -> 2312 total

__global__ __launch_bounds__(256) void k1_stats(const int* __restrict__ ids,
                                                const float* __restrict__ wemb,
                                                float* __restrict__ partials,
                                                int tpb)
{
    __shared__ float xs[32][132];   // 32 tokens x 128 floats, padded to 132
    __shared__ float nrm[32][8];
    const int t = threadIdx.x;
    const int b = blockIdx.x;

    float g[4][4];
#pragma unroll
    for (int i = 0; i < 4; ++i)
#pragma unroll
        for (int j = 0; j < 4; ++j) g[i][j] = 0.f;
    float sx = 0.f, hh = 0.f, s2 = 0.f;

    const int d_g = t >> 4;                 // t<128: Gram task (d, 4x4 tile)
    const int r0  = ((t >> 2) & 3) << 2;
    const int c0  = (t & 3) << 2;
    const int u   = t & 127;                // t>=128: (d,s) task
    const int d_s = u >> 4;
    const int s_s = u & 15;

    const int nchunks = tpb >> 5;
    for (int ch = 0; ch < nchunks; ++ch) {
        const int n0 = b * tpb + ch * 32;
        // ---- load 32 token rows (coalesced: 32 lanes x float4 = one 512B row) ----
#pragma unroll
        for (int rep = 0; rep < 4; ++rep) {
            int i = t + rep * 256;
            int n = i >> 5, f = i & 31;
            int id = ids[n0 + n];
            float4 v = *(const float4*)(wemb + (size_t)id * 128 + f * 4);
            *(float4*)(&xs[n][f * 4]) = v;
        }
        __syncthreads();
        // ---- per-(n,d) norms: 256 threads = 32x8 ----
        {
            int n = t >> 3, dd = t & 7;
            const float* xp = &xs[n][dd * 16];
            float4 a = *(const float4*)(xp);
            float4 bq = *(const float4*)(xp + 4);
            float4 c = *(const float4*)(xp + 8);
            float4 dq = *(const float4*)(xp + 12);
            float acc = a.x*a.x + a.y*a.y + a.z*a.z + a.w*a.w;
            acc += bq.x*bq.x + bq.y*bq.y + bq.z*bq.z + bq.w*bq.w;
            acc += c.x*c.x + c.y*c.y + c.z*c.z + c.w*c.w;
            acc += dq.x*dq.x + dq.y*dq.y + dq.z*dq.z + dq.w*dq.w;
            nrm[n][dd] = acc;
        }
        __syncthreads();
        // ---- accumulate stats over the chunk ----
        if (t < 128) {
            for (int n = 0; n < 32; ++n) {
                const float* xp = &xs[n][d_g * 16];
                float4 av = *(const float4*)(xp + r0);
                float4 bv = *(const float4*)(xp + c0);
                float aa[4] = {av.x, av.y, av.z, av.w};
                float bb[4] = {bv.x, bv.y, bv.z, bv.w};
#pragma unroll
                for (int i = 0; i < 4; ++i)
#pragma unroll
                    for (int j = 0; j < 4; ++j)
                        g[i][j] = fmaf(aa[i], bb[j], g[i][j]);
            }
        } else {
            for (int n = 0; n < 32; ++n) {
                float xv = xs[n][d_s * 16 + s_s];
                float nv = nrm[n][d_s];
                sx += xv;
                hh = fmaf(nv, xv, hh);
                if (s_s == 0) s2 = fmaf(nv, nv, s2);
            }
        }
        __syncthreads();
    }
    float* pb = partials + (size_t)b * ST;
    if (t < 128) {
        const int base = d_g * 256;
#pragma unroll
        for (int i = 0; i < 4; ++i)
#pragma unroll
            for (int j = 0; j < 4; ++j)
                pb[base + (r0 + i) * 16 + (c0 + j)] = g[i][j];
    } else {
        pb[2048 + d_s * 16 + s_s] = sx;
        pb[2176 + d_s * 16 + s_s] = hh;
        if (s_s == 0) pb[2304 + d_s] = s2;
    }
}

// ---- stage A: fold nb blocks down to 32, in place. grid (10, 32). ----
__global__ __launch_bounds__(256) void k2a_reduce(float* __restrict__ partials, int nb)
{
    const int idx = blockIdx.x * 256 + threadIdx.x;
    if (idx >= 2312) return;
    const int y = blockIdx.y;          // 0..31
    float acc[8] = {0.f, 0.f, 0.f, 0.f, 0.f, 0.f, 0.f, 0.f};
    int b = y;
    while (b + 7 * 32 < nb) {
#pragma unroll
        for (int u = 0; u < 8; ++u)
            acc[u] += partials[(size_t)(b + u * 32) * ST + idx];
        b += 8 * 32;
    }
    while (b < nb) { acc[0] += partials[(size_t)b * ST + idx]; b += 32; }
    float s = ((acc[0] + acc[1]) + (acc[2] + acc[3]))
            + ((acc[4] + acc[5]) + (acc[6] + acc[7]));
    partials[(size_t)y * ST + idx] = s;
}

// ---- stage B: sum the 32 survivors (L2-resident, fully unrolled). grid 10. ----
__global__ __launch_bounds__(256) void k2b_reduce(const float* __restrict__ partials,
                                                  float* __restrict__ stats)
{
    const int idx = blockIdx.x * 256 + threadIdx.x;
    if (idx >= 2312) return;
    float acc[8] = {0.f, 0.f, 0.f, 0.f, 0.f, 0.f, 0.f, 0.f};
#pragma unroll
    for (int j = 0; j < 4; ++j)
#pragma unroll
        for (int u = 0; u < 8; ++u)
            acc[u] += partials[(size_t)(j * 8 + u) * ST + idx];
    stats[idx] = ((acc[0] + acc[1]) + (acc[2] + acc[3]))
               + ((acc[4] + acc[5]) + (acc[6] + acc[7]));
}

__global__ __launch_bounds__(128) void k3_final(const float* __restrict__ stats,
                                                const float* __restrict__ centroids,
                                                float2* __restrict__ ab)
{
    __shared__ float st[2312];
    const int t = threadIdx.x;
    for (int i = t; i < 2312; i += 128) st[i] = stats[i];
    __syncthreads();
    const int k = t;   // 128 threads, one per code

    double Sn[8], Sn_tot = 0.0, S2_tot = 0.0;
#pragma unroll
    for (int d = 0; d < 8; ++d) {
        double s = 0.0;
        for (int ss = 0; ss < 16; ++ss) s += (double)st[d * 256 + ss * 17];
        Sn[d] = s; Sn_tot += s;
        S2_tot += (double)st[2304 + d];
    }
    double sr = -Sn_tot, sr2 = S2_tot;
    double ncd[8];
    for (int d = 0; d < 8; ++d) {
        const float* cp = centroids + d * 2048 + k * 16;
        float cv[16];
#pragma unroll
        for (int s = 0; s < 16; ++s) cv[s] = cp[s];
        double nc = 0, cdSx = 0, ch = 0, cGc = 0;
        for (int s = 0; s < 16; ++s) {
            nc   += (double)cv[s] * cv[s];
            cdSx += (double)cv[s] * st[2048 + d * 16 + s];
            ch   += (double)cv[s] * st[2176 + d * 16 + s];
            double rd = 0;
            for (int s2i = 0; s2i < 16; ++s2i)
                rd += (double)st[d * 256 + s * 16 + s2i] * cv[s2i];
            cGc += (double)cv[s] * rd;
        }
        ncd[d] = nc;
        sr  += 2.0 * cdSx - (double)NTOK * nc;
        sr2 += 4.0 * cGc + (double)NTOK * nc * nc + 2.0 * nc * Sn[d]
               - 4.0 * ch - 4.0 * nc * cdSx;
    }
    const double M = (double)NTOK * 8.0;
    double mean = sr / M;
    double var  = sr2 / M - mean * mean;
    float alpha = (float)(1.0 / sqrt(var + (double)EPS));
#pragma unroll
    for (int d = 0; d < 8; ++d) {
        float beta = (float)((double)alpha * (-ncd[d] - mean));
        ab[d * 128 + k] = make_float2(2.f * alpha, beta);
    }
}

// 4 tokens/thread, one d per blockIdx.y, 256-thread blocks, launch_bounds(256,4).
// R9's k-loop (LDS-broadcast c rows, pk_fma), two deltas only:
//  - (2a,b) per k comes from per-lane preloaded regs via v_readlane in two
//    half-loops (k<64 from g_lo, k>=64 from g_hi) -> 4 DS ops/k, not 5.
//  - winner centroid re-read from global (L1-hot), not LDS.
__global__ __launch_bounds__(256, 4) void k4_main(const int* __restrict__ ids,
                                                  const float* __restrict__ wemb,
                                                  const float* __restrict__ centroids,
                                                  const float2* __restrict__ ab,
                                                  float* __restrict__ out)
{
    __shared__ float cs[128 * 16];    // 8KB: centroids for this d

    const int t = threadIdx.x;        // 0..255
    const int d = blockIdx.y;
    const int lane = t & 63;
    const float* cd = centroids + (size_t)d * 2048;

    // stage centroids: 512 float4 -> 2 per thread
#pragma unroll
    for (int i = 0; i < 2; ++i)
        ((float4*)cs)[t + i * 256] = ((const float4*)cd)[t + i * 256];

    // per-lane (2a,b): lane l holds k=l (lo) and k=64+l (hi)
    const float2 g_lo = ab[(size_t)d * 128 + lane];
    const float2 g_hi = ab[(size_t)d * 128 + 64 + lane];

    const int nbase = blockIdx.x * 1024 + t;   // 4 tokens, stride 256
    v2f x[4][8];
    v2f nxv[4];
    float best[4];
    int   code[4];
#pragma unroll
    for (int j = 0; j < 4; ++j) {
        const int n = nbase + j * 256;
        const float* xp = wemb + (size_t)ids[n] * 128 + d * 16;
        float s = 0.f;
#pragma unroll
        for (int q = 0; q < 4; ++q) {
            float4 v = *(const float4*)(xp + q * 4);
            x[j][q * 2]     = (v2f){v.x, v.y};
            x[j][q * 2 + 1] = (v2f){v.z, v.w};
            s += v.x * v.x + v.y * v.y + v.z * v.z + v.w * v.w;
        }
        nxv[j] = (v2f){-0.5f * s, 0.f}; // score = 2a*(dot - nx/2) + beta
        best[j] = -3.4e38f;
        code[j] = 0;
    }

    __syncthreads();

#define KHALF(GSRC, KOFF)                                                    \
    _Pragma("unroll 2")                                                      \
    for (int k = 0; k < 64; ++k) {                                           \
        const int kk = k + (KOFF);                                           \
        const float4 c0 = *(const float4*)(&cs[kk * 16 + 0]);                \
        const float4 c1 = *(const float4*)(&cs[kk * 16 + 4]);                \
        const float4 c2 = *(const float4*)(&cs[kk * 16 + 8]);                \
        const float4 c3 = *(const float4*)(&cs[kk * 16 + 12]);               \
        const float ga_ = rlane(GSRC.x, k);                                  \
        const float gb_ = rlane(GSRC.y, k);                                  \
        const v2f cc0 = (v2f){c0.x, c0.y}, cc1 = (v2f){c0.z, c0.w};          \
        const v2f cc2 = (v2f){c1.x, c1.y}, cc3 = (v2f){c1.z, c1.w};          \
        const v2f cc4 = (v2f){c2.x, c2.y}, cc5 = (v2f){c2.z, c2.w};          \
        const v2f cc6 = (v2f){c3.x, c3.y}, cc7 = (v2f){c3.z, c3.w};          \
        _Pragma("unroll")                                                    \
        for (int j = 0; j < 4; ++j) {                                        \
            v2f a = __builtin_elementwise_fma(cc0, x[j][0], nxv[j]);         \
            a = __builtin_elementwise_fma(cc1, x[j][1], a);                  \
            a = __builtin_elementwise_fma(cc2, x[j][2], a);                  \
            a = __builtin_elementwise_fma(cc3, x[j][3], a);                  \
            a = __builtin_elementwise_fma(cc4, x[j][4], a);                  \
            a = __builtin_elementwise_fma(cc5, x[j][5], a);                  \
            a = __builtin_elementwise_fma(cc6, x[j][6], a);                  \
            a = __builtin_elementwise_fma(cc7, x[j][7], a);                  \
            float acc = a[0] + a[1];                                         \
            float sc = fmaf(ga_, acc, gb_);                                  \
            bool p = sc > best[j];   /* strict > keeps FIRST max */          \
            best[j] = p ? sc : best[j];                                      \
            code[j] = p ? kk : code[j];                                      \
        }                                                                    \
    }

    KHALF(g_lo, 0)
    KHALF(g_hi, 64)
#undef KHALF

#pragma unroll
    for (int j = 0; j < 4; ++j) {
        const int n = nbase + j * 256;
        const float* cw = cd + code[j] * 16;   // global, L1-hot 8KB set
        float* op = out + (size_t)n * 128 + d * 16;
#pragma unroll
        for (int q = 0; q < 4; ++q) {
            float4 cv = *(const float4*)(cw + q * 4);
            float x0 = x[j][q * 2][0],     x1 = x[j][q * 2][1];
            float x2 = x[j][q * 2 + 1][0], x3 = x[j][q * 2 + 1][1];
            float4 o;
            // match reference: out = x + (c - x) in fp32 (not just c)
            o.x = x0 + (cv.x - x0);
            o.y = x1 + (cv.y - x1);
            o.z = x2 + (cv.z - x2);
            o.w = x3 + (cv.w - x3);
            *(float4*)(op + q * 4) = o;
        }
    }
}

extern "C" void kernel_launch(void* const* d_in, const int* in_sizes, int n_in,
                              void* d_out, int out_size, void* d_ws, size_t ws_size,
                              hipStream_t stream)
{
    const int* ids    = (const int*)d_in[0];
    const float* wemb = (const float*)d_in[1];
    const float* cent = (const float*)d_in[2];
    float* out = (float*)d_out;
    float* ws  = (float*)d_ws;

    // choose pass-1 block count by available workspace (2048 preferred: 8
    // blocks/CU, 16 waves -> hides the cold-gather HBM latency)
    int p1b = 2048;
    if (ws_size < ((size_t)2048 * ST + 2320 + 2048) * 4) p1b = 1024;
    if (ws_size < ((size_t)1024 * ST + 2320 + 2048) * 4) p1b = 512;
    if (ws_size < ((size_t)512  * ST + 2320 + 2048) * 4) p1b = 256;
    if (ws_size < ((size_t)256  * ST + 2320 + 2048) * 4) p1b = 128;
    const int tpb = NTOK / p1b;

    float* partials = ws;
    float* stats    = ws + (size_t)p1b * ST;
    float2* ab      = (float2*)(stats + 2320);

    hipLaunchKernelGGL(k1_stats,   dim3(p1b),     dim3(256), 0, stream, ids, wemb, partials, tpb);
    hipLaunchKernelGGL(k2a_reduce, dim3(10, 32),  dim3(256), 0, stream, partials, p1b);
    hipLaunchKernelGGL(k2b_reduce, dim3(10),      dim3(256), 0, stream, partials, stats);
    hipLaunchKernelGGL(k3_final,   dim3(1),       dim3(128), 0, stream, stats, cent, ab);
    hipLaunchKernelGGL(k4_main,    dim3(128, 8),  dim3(256), 0, stream, ids, wemb, cent, ab, out);
}